// Round 6
// baseline (465.054 us; speedup 1.0000x reference)
//
#include <hip/hip_runtime.h>

// Problem constants (match reference setup_inputs)
#define NN 100000
#define NE 600000
#define NG 256
#define HID 128
#define BN_EPS 1e-5f

#define SCAN_TILE 1024
#define NTILES ((NN + SCAN_TILE - 1) / SCAN_TILE)  // 98

// ---------------- histogram of dst (in-degree) ----------------

__global__ __launch_bounds__(256) void hist_kernel(const int* __restrict__ dst, int* __restrict__ cnt) {
    int e = blockIdx.x * blockDim.x + threadIdx.x;
    if (e < NE) atomicAdd(&cnt[dst[e]], 1);
}

__global__ __launch_bounds__(256) void dinv_kernel(const int* __restrict__ cnt, float* __restrict__ dinv) {
    int n = blockIdx.x * blockDim.x + threadIdx.x;
    if (n < NN) dinv[n] = rsqrtf((float)cnt[n] + 1.0f);
}

// ---------------- 2-level exclusive scan of cnt -> row_start ----------------

__global__ __launch_bounds__(256) void scan_a(const int* __restrict__ cnt, int* __restrict__ rs,
                                              int* __restrict__ tsum) {
    __shared__ int s[256];
    int t = threadIdx.x;
    int base = blockIdx.x * SCAN_TILE;
    int idx = base + t * 4;
    int v0 = (idx + 0 < NN) ? cnt[idx + 0] : 0;
    int v1 = (idx + 1 < NN) ? cnt[idx + 1] : 0;
    int v2 = (idx + 2 < NN) ? cnt[idx + 2] : 0;
    int v3 = (idx + 3 < NN) ? cnt[idx + 3] : 0;
    int local = v0 + v1 + v2 + v3;
    s[t] = local;
    __syncthreads();
    for (int off = 1; off < 256; off <<= 1) {
        int x = (t >= off) ? s[t - off] : 0;
        __syncthreads();
        s[t] += x;
        __syncthreads();
    }
    int pre = s[t] - local;  // exclusive prefix within tile
    if (t == 255) tsum[blockIdx.x] = s[255];
    if (idx + 0 < NN) rs[idx + 0] = pre; pre += v0;
    if (idx + 1 < NN) rs[idx + 1] = pre; pre += v1;
    if (idx + 2 < NN) rs[idx + 2] = pre; pre += v2;
    if (idx + 3 < NN) rs[idx + 3] = pre;
}

__global__ __launch_bounds__(128) void scan_b(int* __restrict__ tsum) {
    __shared__ int s[128];
    int t = threadIdx.x;
    int v = (t < NTILES) ? tsum[t] : 0;
    s[t] = v;
    __syncthreads();
    for (int off = 1; off < 128; off <<= 1) {
        int x = (t >= off) ? s[t - off] : 0;
        __syncthreads();
        s[t] += x;
        __syncthreads();
    }
    if (t < NTILES) tsum[t] = s[t] - v;  // exclusive
}

__global__ __launch_bounds__(256) void scan_c(int* __restrict__ rs, const int* __restrict__ tsum,
                                              int* __restrict__ cursor) {
    int t = threadIdx.x;
    int base = blockIdx.x * SCAN_TILE;
    int off = tsum[blockIdx.x];
    for (int k = 0; k < 4; k++) {
        int idx = base + t * 4 + k;
        if (idx < NN) {
            int v = rs[idx] + off;
            rs[idx] = v;
            cursor[idx] = v;
        }
    }
    if (blockIdx.x == 0 && t == 0) rs[NN] = NE;
}

// ---------------- bucket edges by dst (also precompute edge weights) ----------------

__global__ __launch_bounds__(256) void bucket_kernel(const int* __restrict__ src, const int* __restrict__ dst,
                                                     const float* __restrict__ dinv,
                                                     int* __restrict__ cursor,
                                                     int* __restrict__ esrc, float* __restrict__ ewt) {
    int e = blockIdx.x * blockDim.x + threadIdx.x;
    if (e < NE) {
        int s = src[e], d = dst[e];
        int pos = atomicAdd(&cursor[d], 1);
        esrc[pos] = s;
        ewt[pos] = dinv[s] * dinv[d];
    }
}

// ---------------- layer 0 part A: aggregate raw x (7-dim) -> xa [NN,8] ----------------

__global__ __launch_bounds__(256) void xagg_kernel(const float* __restrict__ x,
                                                   const int* __restrict__ rs,
                                                   const int* __restrict__ esrc,
                                                   const float* __restrict__ ewt,
                                                   const float* __restrict__ dinv,
                                                   float* __restrict__ xa) {
    int t = blockIdx.x * blockDim.x + threadIdx.x;
    int f = t & 7;
    int n = t >> 3;
    if (n >= NN) return;
    float acc = 0.f;
    if (f < 7) {
        float di = dinv[n];
        acc = x[n * 7 + f] * di * di;
        int e0 = rs[n], e1 = rs[n + 1];
        int e = e0;
        for (; e + 1 < e1; e += 2) {
            int s0 = esrc[e], s1 = esrc[e + 1];
            float w0 = ewt[e], w1 = ewt[e + 1];
            float a0 = x[s0 * 7 + f];
            float a1 = x[s1 * 7 + f];
            acc = fmaf(a0, w0, acc);
            acc = fmaf(a1, w1, acc);
        }
        if (e < e1) acc = fmaf(x[esrc[e] * 7 + f], ewt[e], acc);
    }
    xa[n * 8 + f] = acc;
}

// ---------------- layer 0 part B: xa @ W0 + b -> BN -> ReLU -> out ----------------

__global__ __launch_bounds__(256) void l0_transform(const float* __restrict__ xa,
                                                    const float* __restrict__ W,
                                                    const float* __restrict__ b,
                                                    const float* __restrict__ gamma,
                                                    const float* __restrict__ beta,
                                                    const float* __restrict__ mean,
                                                    const float* __restrict__ var,
                                                    float* __restrict__ out) {
    int j = threadIdx.x & 127;
    int half = threadIdx.x >> 7;
    float w[7];
#pragma unroll
    for (int k = 0; k < 7; k++) w[k] = W[k * HID + j];
    float bj = b[j];
    float scale = gamma[j] * rsqrtf(var[j] + BN_EPS);
    float mj = mean[j], bt = beta[j];
    __shared__ float s[32][8];
    int r = threadIdx.x >> 3, f = threadIdx.x & 7;
    for (int n0 = blockIdx.x * 32; n0 < NN; n0 += gridDim.x * 32) {
        __syncthreads();
        s[r][f] = xa[(n0 + r) * 8 + f];
        __syncthreads();
        int mend = half * 16 + 16;
        for (int m = half * 16; m < mend; m++) {
            float o = bj;
#pragma unroll
            for (int k = 0; k < 7; k++) o = fmaf(s[m][k], w[k], o);
            out[(size_t)(n0 + m) * HID + j] = fmaxf(fmaf(o - mj, scale, bt), 0.f);
        }
    }
}

// ---------------- layers 1/2 matmul: h [NN,128] @ W [128,128] -> hl ----------------
// 2-D register tiling: 256 thr = 16 tx (col groups) x 16 ty (row groups),
// each thread an 8x8 micro-tile (rows ty + rr*16, cols {4tx..4tx+3, 64+4tx..}).
// k blocked x4 (KB=32): h chunk [128][32] XOR-swizzled + W chunk [32][128] in
// LDS (32 KB); next chunk prefetched into registers during compute.
// LDS reads are broadcast-heavy: 16 ds_read_b128 per 256 FMAs per thread.

__global__ __launch_bounds__(256, 2) void gcn_mm128(const float* __restrict__ hin,
                                                    const float* __restrict__ W,
                                                    float* __restrict__ hl) {
    __shared__ float4 hbuf[1024];  // [r][k4^(r&7)] 128 rows x 8 float4
    __shared__ float4 wbuf[1024];  // [k][c4]       32 k    x 32 float4
    int t = threadIdx.x;
    int tx = t & 15;
    int ty = t >> 4;
    int tys = ty & 7;  // swizzle key for this thread's rows
    int row0 = blockIdx.x * 128;

    const float4* hin4 = (const float4*)hin;
    const float4* W4   = (const float4*)W;
    float4* out4       = (float4*)hl;

    float4 accA[8], accB[8];
#pragma unroll
    for (int i = 0; i < 8; i++) {
        accA[i] = make_float4(0.f, 0.f, 0.f, 0.f);
        accB[i] = make_float4(0.f, 0.f, 0.f, 0.f);
    }

    // prologue: load chunk kb=0 into registers
    float4 ph[4], pw[4];
#pragma unroll
    for (int i = 0; i < 4; i++) {
        int f = t + i * 256;               // 0..1023
        int r = f >> 3, k4 = f & 7;
        int grow = row0 + r;
        ph[i] = (grow < NN) ? hin4[(size_t)grow * 32 + k4] : make_float4(0.f, 0.f, 0.f, 0.f);
        int k = f >> 5, c4 = f & 31;
        pw[i] = W4[(size_t)k * 32 + c4];
    }

    for (int kb = 0; kb < 4; kb++) {
        if (kb > 0) __syncthreads();       // prior compute done reading LDS
#pragma unroll
        for (int i = 0; i < 4; i++) {
            int f = t + i * 256;
            int r = f >> 3, k4 = f & 7;
            hbuf[r * 8 + (k4 ^ (r & 7))] = ph[i];
            wbuf[f] = pw[i];
        }
        __syncthreads();
        if (kb < 3) {                      // prefetch next chunk (hidden under compute)
#pragma unroll
            for (int i = 0; i < 4; i++) {
                int f = t + i * 256;
                int r = f >> 3, k4 = f & 7;
                int grow = row0 + r;
                ph[i] = (grow < NN) ? hin4[(size_t)grow * 32 + (kb + 1) * 8 + k4]
                                    : make_float4(0.f, 0.f, 0.f, 0.f);
                int k = f >> 5, c4 = f & 31;
                pw[i] = W4[(size_t)((kb + 1) * 32 + k) * 32 + c4];
            }
        }
#pragma unroll
        for (int k4 = 0; k4 < 8; k4++) {
            float4 hv[8];
#pragma unroll
            for (int rr = 0; rr < 8; rr++)
                hv[rr] = hbuf[(ty + rr * 16) * 8 + (k4 ^ tys)];
            float4 wa[4], wb[4];
#pragma unroll
            for (int kk = 0; kk < 4; kk++) {
                wa[kk] = wbuf[(k4 * 4 + kk) * 32 + tx];
                wb[kk] = wbuf[(k4 * 4 + kk) * 32 + 16 + tx];
            }
#pragma unroll
            for (int kk = 0; kk < 4; kk++) {
#pragma unroll
                for (int rr = 0; rr < 8; rr++) {
                    float hs = ((const float*)&hv[rr])[kk];
                    accA[rr].x = fmaf(hs, wa[kk].x, accA[rr].x);
                    accA[rr].y = fmaf(hs, wa[kk].y, accA[rr].y);
                    accA[rr].z = fmaf(hs, wa[kk].z, accA[rr].z);
                    accA[rr].w = fmaf(hs, wa[kk].w, accA[rr].w);
                    accB[rr].x = fmaf(hs, wb[kk].x, accB[rr].x);
                    accB[rr].y = fmaf(hs, wb[kk].y, accB[rr].y);
                    accB[rr].z = fmaf(hs, wb[kk].z, accB[rr].z);
                    accB[rr].w = fmaf(hs, wb[kk].w, accB[rr].w);
                }
            }
        }
    }

#pragma unroll
    for (int rr = 0; rr < 8; rr++) {
        int grow = row0 + ty + rr * 16;
        if (grow < NN) {
            out4[(size_t)grow * 32 + tx]      = accA[rr];
            out4[(size_t)grow * 32 + 16 + tx] = accB[rr];
        }
    }
}

// ---------------- gather-aggregate + self-loop + bias + BN + ReLU ----------------

__global__ __launch_bounds__(256) void gather_bn(const float* __restrict__ hl,
                                                 const int* __restrict__ rs,
                                                 const int* __restrict__ esrc,
                                                 const float* __restrict__ ewt,
                                                 const float* __restrict__ dinv,
                                                 const float* __restrict__ b,
                                                 const float* __restrict__ gamma,
                                                 const float* __restrict__ beta,
                                                 const float* __restrict__ mean,
                                                 const float* __restrict__ var,
                                                 float* __restrict__ out) {
    int t = blockIdx.x * blockDim.x + threadIdx.x;
    int lane = t & 31;
    int n = t >> 5;
    if (n >= NN) return;
    const float4* hl4 = (const float4*)hl;
    float di = dinv[n];
    float4 self = hl4[(size_t)n * 32 + lane];
    float4 bb = ((const float4*)b)[lane];
    float dsq = di * di;
    float4 acc;
    acc.x = fmaf(self.x, dsq, bb.x);
    acc.y = fmaf(self.y, dsq, bb.y);
    acc.z = fmaf(self.z, dsq, bb.z);
    acc.w = fmaf(self.w, dsq, bb.w);
    int e0 = rs[n], e1 = rs[n + 1];
    int e = e0;
    for (; e + 1 < e1; e += 2) {
        int s0 = esrc[e], s1 = esrc[e + 1];
        float w0 = ewt[e], w1 = ewt[e + 1];
        float4 v0 = hl4[(size_t)s0 * 32 + lane];
        float4 v1 = hl4[(size_t)s1 * 32 + lane];
        acc.x = fmaf(v0.x, w0, acc.x); acc.y = fmaf(v0.y, w0, acc.y);
        acc.z = fmaf(v0.z, w0, acc.z); acc.w = fmaf(v0.w, w0, acc.w);
        acc.x = fmaf(v1.x, w1, acc.x); acc.y = fmaf(v1.y, w1, acc.y);
        acc.z = fmaf(v1.z, w1, acc.z); acc.w = fmaf(v1.w, w1, acc.w);
    }
    if (e < e1) {
        int s0 = esrc[e];
        float w0 = ewt[e];
        float4 v0 = hl4[(size_t)s0 * 32 + lane];
        acc.x = fmaf(v0.x, w0, acc.x); acc.y = fmaf(v0.y, w0, acc.y);
        acc.z = fmaf(v0.z, w0, acc.z); acc.w = fmaf(v0.w, w0, acc.w);
    }
    float4 ga = ((const float4*)gamma)[lane];
    float4 be = ((const float4*)beta)[lane];
    float4 me = ((const float4*)mean)[lane];
    float4 va = ((const float4*)var)[lane];
    float4 o;
    o.x = fmaxf(fmaf(acc.x - me.x, ga.x * rsqrtf(va.x + BN_EPS), be.x), 0.f);
    o.y = fmaxf(fmaf(acc.y - me.y, ga.y * rsqrtf(va.y + BN_EPS), be.y), 0.f);
    o.z = fmaxf(fmaf(acc.z - me.z, ga.z * rsqrtf(va.z + BN_EPS), be.z), 0.f);
    o.w = fmaxf(fmaf(acc.w - me.w, ga.w * rsqrtf(va.w + BN_EPS), be.w), 0.f);
    ((float4*)out)[(size_t)n * 32 + lane] = o;
}

// ---------------- global mean pool (batch is sorted) ----------------

__global__ __launch_bounds__(1024) void pool_kernel(const float* __restrict__ h,
                                                    const int* __restrict__ batch,
                                                    float* __restrict__ lig) {
    int g = blockIdx.x;
    int lane = threadIdx.x & 31;   // float4 index within feature row
    int row = threadIdx.x >> 5;    // 0..31
    __shared__ int se[2];
    if (threadIdx.x < 2) {
        int target = g + threadIdx.x;
        int lo = 0, hi = NN;
        while (lo < hi) {
            int mid = (lo + hi) >> 1;
            if (batch[mid] < target) lo = mid + 1; else hi = mid;
        }
        se[threadIdx.x] = lo;
    }
    __syncthreads();
    int start = se[0], end = se[1];
    const float4* h4 = (const float4*)h;
    float4 acc = make_float4(0.f, 0.f, 0.f, 0.f);
    for (int n = start + row; n < end; n += 32) {
        float4 v = h4[(size_t)n * 32 + lane];
        acc.x += v.x; acc.y += v.y; acc.z += v.z; acc.w += v.w;
    }
    __shared__ float4 part[32][32];
    part[row][lane] = acc;
    __syncthreads();
#pragma unroll
    for (int off = 16; off >= 1; off >>= 1) {
        if (row < off) {
            float4 a = part[row][lane];
            float4 c = part[row + off][lane];
            a.x += c.x; a.y += c.y; a.z += c.z; a.w += c.w;
            part[row][lane] = a;
        }
        __syncthreads();
    }
    if (row == 0) {
        float inv = 1.0f / fmaxf((float)(end - start), 1.0f);
        float4 a = part[0][lane];
        a.x *= inv; a.y *= inv; a.z *= inv; a.w *= inv;
        ((float4*)lig)[g * 32 + lane] = a;
    }
}

// ---------------- pocket MLP: 28 -> 64 -> 64 ----------------

__global__ __launch_bounds__(64) void pocket_kernel(const float* __restrict__ pocket,
                                                    const float* __restrict__ pw1,
                                                    const float* __restrict__ pb1,
                                                    const float* __restrict__ pw2,
                                                    const float* __restrict__ pb2,
                                                    float* __restrict__ p) {
    int j = threadIdx.x;
    __shared__ float t1[64];
    float acc = pb1[j];
    for (int k = 0; k < 28; k++) acc = fmaf(pocket[k], pw1[k * 64 + j], acc);
    t1[j] = fmaxf(acc, 0.f);
    __syncthreads();
    float acc2 = pb2[j];
    for (int k = 0; k < 64; k++) acc2 = fmaf(t1[k], pw2[k * 64 + j], acc2);
    p[j] = acc2;
}

// ---------------- classifier: concat(lig, p) -> 96 -> 1 ----------------

__global__ __launch_bounds__(96) void cls_kernel(const float* __restrict__ lig,
                                                 const float* __restrict__ p,
                                                 const float* __restrict__ cw1,
                                                 const float* __restrict__ cb1,
                                                 const float* __restrict__ cw2,
                                                 const float* __restrict__ cb2,
                                                 float* __restrict__ out) {
    int g = blockIdx.x;
    int j = threadIdx.x;
    __shared__ float emb[192];
    __shared__ float hid[96];
    for (int k = j; k < HID; k += 96) emb[k] = lig[g * HID + k];
    for (int k = j; k < 64; k += 96) emb[HID + k] = p[k];
    __syncthreads();
    float acc = cb1[j];
    for (int k = 0; k < 192; k++) acc = fmaf(emb[k], cw1[k * 96 + j], acc);
    hid[j] = fmaxf(acc, 0.f) * cw2[j];
    __syncthreads();
    if (j == 0) {
        float s = cb2[0];
        for (int k = 0; k < 96; k++) s += hid[k];
        out[g] = s;
    }
}

extern "C" void kernel_launch(void* const* d_in, const int* in_sizes, int n_in,
                              void* d_out, int out_size, void* d_ws, size_t ws_size,
                              hipStream_t stream) {
    const float* x        = (const float*)d_in[0];
    const int*   eidx     = (const int*)d_in[1];
    const int*   batch    = (const int*)d_in[2];
    const float* pocket   = (const float*)d_in[3];
    const float* W0 = (const float*)d_in[4];
    const float* b0 = (const float*)d_in[5];
    const float* W1 = (const float*)d_in[6];
    const float* b1 = (const float*)d_in[7];
    const float* W2 = (const float*)d_in[8];
    const float* b2 = (const float*)d_in[9];
    const float* bn_gamma = (const float*)d_in[10];
    const float* bn_beta  = (const float*)d_in[11];
    const float* bn_mean  = (const float*)d_in[12];
    const float* bn_var   = (const float*)d_in[13];
    const float* pw1 = (const float*)d_in[14]; const float* pb1 = (const float*)d_in[15];
    const float* pw2 = (const float*)d_in[16]; const float* pb2 = (const float*)d_in[17];
    const float* cw1 = (const float*)d_in[18]; const float* cb1 = (const float*)d_in[19];
    const float* cw2 = (const float*)d_in[20]; const float* cb2 = (const float*)d_in[21];
    float* out = (float*)d_out;

    // Workspace layout (4-byte units, A/B 16B-aligned):
    float* ws   = (float*)d_ws;
    float* dinv = ws;                                   // NN
    int*   cnt  = (int*)(ws + NN);                      // NN (hist, then cursor)
    int*   rs   = cnt + NN;                             // NN+1
    int*   tsum = rs + NN + 1;                          // 128
    int*   esrc = tsum + 128;                           // NE
    float* ewt  = (float*)(esrc + NE);                  // NE
    float* xa   = ewt + NE;                             // NN*8
    size_t head = (size_t)NN * 2 + (NN + 1) + 128 + (size_t)NE * 2 + (size_t)NN * 8;
    head = (head + 3) & ~(size_t)3;                     // 16B align
    float* A    = ws + head;                            // NN*HID
    float* B    = A + (size_t)NN * HID;                 // NN*HID
    float* lig  = B + (size_t)NN * HID;                 // NG*HID
    float* pv   = lig + (size_t)NG * HID;               // 64

    const int* srcp = eidx;
    const int* dstp = eidx + NE;

    // ---- build CSR (by dst) + dinv + edge weights ----
    hipMemsetAsync(cnt, 0, NN * sizeof(int), stream);
    hist_kernel<<<(NE + 255) / 256, 256, 0, stream>>>(dstp, cnt);
    dinv_kernel<<<(NN + 255) / 256, 256, 0, stream>>>(cnt, dinv);
    scan_a<<<NTILES, 256, 0, stream>>>(cnt, rs, tsum);
    scan_b<<<1, 128, 0, stream>>>(tsum);
    scan_c<<<NTILES, 256, 0, stream>>>(rs, tsum, cnt);  // cnt becomes cursor
    bucket_kernel<<<(NE + 255) / 256, 256, 0, stream>>>(srcp, dstp, dinv, cnt, esrc, ewt);

    // ---- layer 0: aggregate x, then transform (A = relu(bn(agg(x) @ W0 + b0))) ----
    xagg_kernel<<<(NN * 8 + 255) / 256, 256, 0, stream>>>(x, rs, esrc, ewt, dinv, xa);
    l0_transform<<<2048, 256, 0, stream>>>(xa, W0, b0,
                                           bn_gamma + 0 * HID, bn_beta + 0 * HID,
                                           bn_mean + 0 * HID, bn_var + 0 * HID, A);

    const int MM_BLOCKS = (NN + 127) / 128;  // 782 tiles

    // ---- layer 1 ----
    gcn_mm128<<<MM_BLOCKS, 256, 0, stream>>>(A, W1, B);
    gather_bn<<<(NN * 32 + 255) / 256, 256, 0, stream>>>(B, rs, esrc, ewt, dinv, b1,
                                                         bn_gamma + 1 * HID, bn_beta + 1 * HID,
                                                         bn_mean + 1 * HID, bn_var + 1 * HID, A);
    // ---- layer 2 ----
    gcn_mm128<<<MM_BLOCKS, 256, 0, stream>>>(A, W2, B);
    gather_bn<<<(NN * 32 + 255) / 256, 256, 0, stream>>>(B, rs, esrc, ewt, dinv, b2,
                                                         bn_gamma + 2 * HID, bn_beta + 2 * HID,
                                                         bn_mean + 2 * HID, bn_var + 2 * HID, A);

    // pool -> lig
    pool_kernel<<<NG, 1024, 0, stream>>>(A, batch, lig);
    // pocket MLP
    pocket_kernel<<<1, 64, 0, stream>>>(pocket, pw1, pb1, pw2, pb2, pv);
    // classifier
    cls_kernel<<<NG, 96, 0, stream>>>(lig, pv, cw1, cb1, cw2, cb2, out);
}